// Round 9
// baseline (1063.426 us; speedup 1.0000x reference)
//
#include <hip/hip_runtime.h>

#define T_LEN 2048
#define C_LEN 8192
#define NHV   32

__device__ __forceinline__ float frcp(float x) { return __builtin_amdgcn_rcpf(x); }
__device__ __forceinline__ float sigm(float x) { return frcp(1.f + __expf(-x)); }

// ---- DPP 16-lane full sum (all lanes receive the row total), pure VALU ----
template<int CTRL>
__device__ __forceinline__ float dpp_mov(float x) {
  int yi = __builtin_amdgcn_update_dpp(0, __builtin_bit_cast(int, x), CTRL, 0xf, 0xf, true);
  return __builtin_bit_cast(float, yi);
}
__device__ __forceinline__ float row_sum16(float x) {
  x += dpp_mov<0xB1>(x);    // quad_perm [1,0,3,2]  (xor 1)
  x += dpp_mov<0x4E>(x);    // quad_perm [2,3,0,1]  (xor 2)
  x += dpp_mov<0x124>(x);   // row_ror:4  (quad g += quad g+1)
  x += dpp_mov<0x128>(x);   // row_ror:8  (adds remaining two quads)
  return x;
}

// ws layout: xqk [b][hk][t][256] floats = 67,108,864 B; xgb float2 after.
#define WS_XQK_BYTES 67108864ULL
#define WS_NEED      (WS_XQK_BYTES + 2ULL*NHV*T_LEN*8ULL)

struct F8 { float v[8]; };

__device__ __forceinline__ F8 ld8(const float* p, bool pred) {
  F8 r;
  if (pred) {
    float4 a = *(const float4*)p, b = *(const float4*)(p + 4);
    r.v[0]=a.x; r.v[1]=a.y; r.v[2]=a.z; r.v[3]=a.w;
    r.v[4]=b.x; r.v[5]=b.y; r.v[6]=b.z; r.v[7]=b.w;
  } else {
#pragma unroll
    for (int i = 0; i < 8; ++i) r.v[i] = 0.f;
  }
  return r;
}

// K1: conv+SiLU for all 8192 channels; l2norm+scale for q/k -> xqk (ws);
//     v -> out (staged; K2 overwrites with o afterwards).
// grid 2048: seg = gx&3 (0=q,1=k,2=v0,3=v1), tc = (gx>>2)&255, b = gx>>10
__global__ __launch_bounds__(256, 4) void k1_prep(
    const float* __restrict__ xin, const float* __restrict__ win,
    float* __restrict__ xqk, float* __restrict__ xv /* = out */)
{
  const int gx  = blockIdx.x;
  const int seg = gx & 3, tc = (gx >> 2) & 255, b = gx >> 10;
  const int tid = threadIdx.x;
  const int hs  = tid >> 4;            // sub-head 0..15
  const int lo  = (tid & 15) * 8;      // channel offset within 2048-seg
  const int ch  = seg * 2048 + hs * 128 + lo;   // global channel

  const float* xb = xin + (size_t)b * T_LEN * C_LEN + ch;

  F8 wt0, wt1, wt2, wt3;
#pragma unroll
  for (int c = 0; c < 8; ++c) {
    float4 w = *(const float4*)(win + (size_t)(ch + c) * 4);
    wt0.v[c] = w.x; wt1.v[c] = w.y; wt2.v[c] = w.z; wt3.v[c] = w.w;
  }

  const int t0 = tc * 8;
  F8 r0 = ld8(xb + (size_t)(t0 - 3) * C_LEN, t0 >= 3);
  F8 r1 = ld8(xb + (size_t)(t0 - 2) * C_LEN, t0 >= 2);
  F8 r2 = ld8(xb + (size_t)(t0 - 1) * C_LEN, t0 >= 1);

  const bool isqk = (seg < 2);
  float* outp = isqk
      ? xqk + ((size_t)(b * 16 + hs) * T_LEN) * 256 + seg * 128 + lo
      : xv  + ((size_t)b * T_LEN) * 4096 + (seg - 2) * 2048 + hs * 128 + lo;
  const size_t ostride = isqk ? 256 : 4096;
  const float qscale = (seg == 0) ? 0.08838834764831845f : 1.f;

#pragma unroll
  for (int dt = 0; dt < 8; ++dt) {
    const int t = t0 + dt;
    F8 cur = ld8(xb + (size_t)t * C_LEN, true);
    F8 y; float sq = 0.f;
#pragma unroll
    for (int c = 0; c < 8; ++c) {
      float s = wt0.v[c]*r0.v[c] + wt1.v[c]*r1.v[c] + wt2.v[c]*r2.v[c] + wt3.v[c]*cur.v[c];
      s = s * sigm(s);
      y.v[c] = s; sq += s * s;
    }
    float rn = 1.f;
    if (isqk) {
      sq = row_sum16(sq);                       // lanes of one head are one DPP row
      rn = rsqrtf(sq + 1e-6f) * qscale;
    }
    float4 oa, ob;
    oa.x=y.v[0]*rn; oa.y=y.v[1]*rn; oa.z=y.v[2]*rn; oa.w=y.v[3]*rn;
    ob.x=y.v[4]*rn; ob.y=y.v[5]*rn; ob.z=y.v[6]*rn; ob.w=y.v[7]*rn;
    float* op = outp + (size_t)t * ostride;
    *(float4*)op = oa; *(float4*)(op + 4) = ob;
    r0 = r1; r1 = r2; r2 = cur;
  }
}

// K1b: {exp(g), beta} per (b,hv,t). grid 512 x 256.
__global__ __launch_bounds__(256) void k1b_gate(
    const float* __restrict__ bin, const float* __restrict__ ain,
    const float* __restrict__ dtb, const float* __restrict__ alg,
    float2* __restrict__ xgb)
{
  const int idx = blockIdx.x * 256 + threadIdx.x;   // = ((b*32+hv)*2048 + t)
  const int b = idx >> 16, hv = (idx >> 11) & 31, t = idx & 2047;
  const size_t src = ((size_t)(b * T_LEN + t)) * NHV + hv;
  const float bt = sigm(bin[src]);
  const float x  = ain[src] + dtb[hv];
  const float sp = fmaxf(x, 0.f) + log1pf(__expf(-fabsf(x)));
  xgb[idx] = make_float2(__expf(-__expf(alg[hv]) * sp), bt);
}

// K2: the scan. 16 lanes/col, S[8]/thread, DPP-only reduction, NO LDS, no barriers.
// v is pre-staged in `outv`; o overwrites it in place.
// grid 512: chunk = bx&7 (16 cols each), hv = (bx>>3)&31, bb = bx>>8
__global__ __launch_bounds__(256, 2) void k2_scan(
    const float* __restrict__ xqk, const float2* __restrict__ xgb,
    float* __restrict__ outv)
{
  const int bx = blockIdx.x;
  const int chunk = bx & 7, hv = (bx >> 3) & 31, bb = bx >> 8;
  const int hk = hv >> 1;
  const int tid = threadIdx.x;
  const int rg = tid & 15;            // rows rg*8 .. rg*8+7 (one DPP row per column)
  const int cc = tid >> 4;            // column 0..15
  const int vcol = hv * 128 + chunk * 16 + cc;

  const float*  qk0 = xqk + ((size_t)(bb * 16 + hk) * T_LEN) * 256 + rg * 8;
  const float2* gbp = xgb + ((size_t)(bb * NHV + hv)) * T_LEN;
  float*        vop = outv + (size_t)bb * T_LEN * 4096 + vcol;

  float S0=0.f,S1=0.f,S2=0.f,S3=0.f,S4=0.f,S5=0.f,S6=0.f,S7=0.f;

#pragma unroll 4
  for (int t = 0; t < T_LEN; ++t) {
    const float* qr = qk0 + (size_t)t * 256;
    const float4 ka = *(const float4*)(qr + 128);
    const float4 kb = *(const float4*)(qr + 132);
    const float4 qa = *(const float4*)(qr);
    const float4 qb = *(const float4*)(qr + 4);
    const float  vv = vop[(size_t)t * 4096];
    const float2 gb = gbp[t];

    float d0 = ka.x*S0 + ka.y*S1 + ka.z*S2 + ka.w*S3;
    float d1 = kb.x*S4 + kb.y*S5 + kb.z*S6 + kb.w*S7;
    float dk = row_sum16(d0 + d1);

    const float eg    = gb.x;
    const float delta = (vv - eg * dk) * gb.y;

    S0 = eg*S0 + ka.x*delta; S1 = eg*S1 + ka.y*delta;
    S2 = eg*S2 + ka.z*delta; S3 = eg*S3 + ka.w*delta;
    S4 = eg*S4 + kb.x*delta; S5 = eg*S5 + kb.y*delta;
    S6 = eg*S6 + kb.z*delta; S7 = eg*S7 + kb.w*delta;

    float o0 = qa.x*S0 + qa.y*S1 + qa.z*S2 + qa.w*S3;
    float o1 = qb.x*S4 + qb.y*S5 + qb.z*S6 + qb.w*S7;
    float o  = row_sum16(o0 + o1);

    if (rg == 0) vop[(size_t)t * 4096] = o;
  }
}

// ============================ FALLBACK (v2, passed @1277us) ============================
#define TILE  32
#define NCOL  16
#define XSS   276
#define OTS   33

__global__ __launch_bounds__(256) void gdn_fused(
    const float* __restrict__ xin, const float* __restrict__ bin,
    const float* __restrict__ ain, const float* __restrict__ win,
    const float* __restrict__ dtb, const float* __restrict__ alg,
    float* __restrict__ out)
{
  const int tid   = threadIdx.x;
  const int bx    = blockIdx.x;
  const int chunk = bx & 7;
  const int hv    = (bx >> 3) & 31;
  const int bb    = bx >> 8;
  const int hk    = hv >> 1;

  const int qch0 = hk * 128;
  const int kch0 = 2048 + hk * 128;
  const int vch0 = 4096 + hv * 128 + chunk * NCOL;

  __shared__ __align__(16) float  xs[TILE][XSS];
  __shared__ __align__(16) float4 wc[272];
  __shared__ float  opT[256 * OTS];
  __shared__ float2 s_gb[TILE];
  __shared__ float  s_rq[TILE], s_rk[TILE];

  for (int i = tid; i < 272; i += 256) {
    int gch = (i < 128) ? (qch0 + i) : (i < 256) ? (kch0 + i - 128) : (vch0 + i - 256);
    wc[i] = *(const float4*)(win + (size_t)gch * 4);
  }

  const int lane = tid & 63;
  const int wv   = tid >> 6;
  const int rg   = lane & 15;
  const int col  = wv * 4 + (lane >> 4);
  const int rg4  = rg * 4;

  const float dtbv = dtb[hv];
  const float nA   = -__expf(alg[hv]);

  float S[8];
#pragma unroll
  for (int m = 0; m < 8; ++m) S[m] = 0.f;

  const float* xb  = xin + (size_t)bb * T_LEN * C_LEN;
  float*       op  = out + (size_t)bb * T_LEN * 4096 + hv * 128 + chunk * NCOL;
  float*       opw = &opT[(wv * 64 + lane) * OTS];

  for (int t0 = 0; t0 < T_LEN; t0 += TILE) {
    __syncthreads();
    for (int idx = tid; idx < TILE * 68; idx += 256) {
      int row = idx / 68;
      int c4  = idx - row * 68;
      int gch = (c4 < 32) ? (qch0 + c4 * 4)
              : (c4 < 64) ? (kch0 + (c4 - 32) * 4)
                          : (vch0 + (c4 - 64) * 4);
      int r = t0 + row - 3;
      const float* gp = xb + (size_t)r * C_LEN + gch;
      float4 a0 = (r     >= 0) ? *(const float4*)(gp)             : make_float4(0,0,0,0);
      float4 a1 = (r + 1 >= 0) ? *(const float4*)(gp + C_LEN)     : make_float4(0,0,0,0);
      float4 a2 = (r + 2 >= 0) ? *(const float4*)(gp + 2 * C_LEN) : make_float4(0,0,0,0);
      float4 a3 =                *(const float4*)(gp + 3 * C_LEN);
      float4 w0 = wc[c4 * 4], w1 = wc[c4 * 4 + 1], w2 = wc[c4 * 4 + 2], w3 = wc[c4 * 4 + 3];
      float4 o4;
      o4.x = a0.x * w0.x + a1.x * w0.y + a2.x * w0.z + a3.x * w0.w;
      o4.y = a0.y * w1.x + a1.y * w1.y + a2.y * w1.z + a3.y * w1.w;
      o4.z = a0.z * w2.x + a1.z * w2.y + a2.z * w2.z + a3.z * w2.w;
      o4.w = a0.w * w3.x + a1.w * w3.y + a2.w * w3.z + a3.w * w3.w;
      o4.x *= sigm(o4.x); o4.y *= sigm(o4.y); o4.z *= sigm(o4.z); o4.w *= sigm(o4.w);
      *(float4*)&xs[row][c4 * 4] = o4;
    }
    if (tid < TILE) {
      int tg = t0 + tid;
      size_t boff = ((size_t)bb * T_LEN + tg) * NHV + hv;
      float  bt = sigm(bin[boff]);
      float  x  = ain[boff] + dtbv;
      float  sp = fmaxf(x, 0.f) + log1pf(__expf(-fabsf(x)));
      s_gb[tid] = make_float2(__expf(nA * sp), bt);
    }
    __syncthreads();
    {
      int ttn = tid >> 3, l8 = tid & 7;
      float sq = 0.f, sk = 0.f;
#pragma unroll
      for (int m = 0; m < 16; ++m) {
        int cc = m * 8 + l8;
        float aq = xs[ttn][cc];
        float ak = xs[ttn][128 + cc];
        sq += aq * aq; sk += ak * ak;
      }
      sq += __shfl_xor(sq, 1); sq += __shfl_xor(sq, 2); sq += __shfl_xor(sq, 4);
      sk += __shfl_xor(sk, 1); sk += __shfl_xor(sk, 2); sk += __shfl_xor(sk, 4);
      if (l8 == 0) {
        s_rq[ttn] = rsqrtf(sq + 1e-6f) * 0.08838834764831845f;
        s_rk[ttn] = rsqrtf(sk + 1e-6f);
      }
    }
    __syncthreads();
    for (int idx = tid; idx < TILE * 64; idx += 256) {
      int row = idx >> 6, c4 = idx & 63;
      float f = (c4 < 32) ? s_rq[row] : s_rk[row];
      float4* p = (float4*)&xs[row][c4 * 4];
      float4 v = *p;
      v.x *= f; v.y *= f; v.z *= f; v.w *= f;
      *p = v;
    }
    __syncthreads();
#pragma unroll 2
    for (int tt = 0; tt < TILE; ++tt) {
      const float* xr = &xs[tt][0];
      float4 k0 = *(const float4*)(xr + 128 + rg4);
      float4 k1 = *(const float4*)(xr + 192 + rg4);
      float  vv = xr[256 + col];
      float4 q0 = *(const float4*)(xr +       rg4);
      float4 q1 = *(const float4*)(xr +  64 + rg4);

      float dk = k0.x*S[0] + k0.y*S[1] + k0.z*S[2] + k0.w*S[3]
               + k1.x*S[4] + k1.y*S[5] + k1.z*S[6] + k1.w*S[7];
      dk += __shfl_xor(dk, 1); dk += __shfl_xor(dk, 2);
      dk += __shfl_xor(dk, 4); dk += __shfl_xor(dk, 8);

      float2 gb    = s_gb[tt];
      float  eg    = gb.x;
      float  delta = (vv - eg * dk) * gb.y;

      S[0] = eg*S[0] + k0.x*delta;  S[1] = eg*S[1] + k0.y*delta;
      S[2] = eg*S[2] + k0.z*delta;  S[3] = eg*S[3] + k0.w*delta;
      S[4] = eg*S[4] + k1.x*delta;  S[5] = eg*S[5] + k1.y*delta;
      S[6] = eg*S[6] + k1.z*delta;  S[7] = eg*S[7] + k1.w*delta;

      float o = q0.x*S[0] + q0.y*S[1] + q0.z*S[2] + q0.w*S[3]
              + q1.x*S[4] + q1.y*S[5] + q1.z*S[6] + q1.w*S[7];
      opw[tt] = o;
    }
    __syncthreads();
    {
      int ttb = tid & 31, colb = tid >> 5;
#pragma unroll
      for (int it = 0; it < 2; ++it) {
        int cc = colb + it * 8;
        const float* pp = &opT[(cc * 16) * OTS + ttb];
        float s = 0.f;
#pragma unroll
        for (int i = 0; i < 16; ++i) s += pp[i * OTS];
        op[(size_t)(t0 + ttb) * 4096 + cc] = s;
      }
    }
  }
}

extern "C" void kernel_launch(void* const* d_in, const int* in_sizes, int n_in,
                              void* d_out, int out_size, void* d_ws, size_t ws_size,
                              hipStream_t stream) {
  (void)in_sizes; (void)n_in; (void)out_size;
  const float* xin = (const float*)d_in[0];
  const float* bin = (const float*)d_in[1];
  const float* ain = (const float*)d_in[2];
  const float* win = (const float*)d_in[3];
  const float* dtb = (const float*)d_in[4];
  const float* alg = (const float*)d_in[5];
  float* out = (float*)d_out;

  if (ws_size >= WS_NEED) {
    float*  xqk = (float*)d_ws;
    float2* xgb = (float2*)((char*)d_ws + WS_XQK_BYTES);
    k1_prep<<<dim3(2048), dim3(256), 0, stream>>>(xin, win, xqk, out);
    k1b_gate<<<dim3(512), dim3(256), 0, stream>>>(bin, ain, dtb, alg, xgb);
    k2_scan<<<dim3(512), dim3(256), 0, stream>>>(xqk, xgb, out);
  } else {
    gdn_fused<<<dim3(512), dim3(256), 0, stream>>>(xin, bin, ain, win, dtb, alg, out);
  }
}